// Round 13
// baseline (1915.859 us; speedup 1.0000x reference)
//
#include <hip/hip_runtime.h>

#define HH 288
#define WW 288
#define HW (HH*WW)

using f16x8  = __attribute__((ext_vector_type(8))) _Float16;
using f32x4  = __attribute__((ext_vector_type(4))) float;

// ---------------- helpers ----------------
__device__ __forceinline__ void fma4x8(float acc[4][8], const float4 a, const float4 b0, const float4 b1) {
  float av[4] = {a.x,a.y,a.z,a.w};
  float bv[8] = {b0.x,b0.y,b0.z,b0.w,b1.x,b1.y,b1.z,b1.w};
#pragma unroll
  for (int i=0;i<4;i++)
#pragma unroll
    for (int j=0;j<8;j++)
      acc[i][j] = fmaf(av[i], bv[j], acc[i][j]);
}

// ---------------- prep: W2t/W3t fp32 transposes ----------------
__global__ __launch_bounds__(256) void prep_kernel(const float* __restrict__ w2, const float* __restrict__ w3,
                                                   float* __restrict__ W2t, float* __restrict__ W3t) {
  int tid = blockIdx.x*256 + threadIdx.x;
  int stride = gridDim.x*256;
  for (int e = tid; e < 9*64*64; e += stride) {
    int tap = e / 4096, ci = (e >> 6) & 63, co = e & 63;
    W2t[e] = w2[(co*64 + ci)*9 + tap];
  }
  for (int e = tid; e < 9*64*128; e += stride) {
    int tap = e / 8192, ci = (e >> 7) & 63, co = e & 127;
    W3t[e] = w3[(co*64 + ci)*9 + tap];
  }
}

// ---------------- conv1: sub_mean + 3x3 (6->64) + relu (R9 version, passing) ----------------
__global__ __launch_bounds__(256) void conv1_kernel(const float* __restrict__ q, const float* __restrict__ k,
                                                    const float* __restrict__ w1, const float* __restrict__ b1,
                                                    float* __restrict__ X1) {
  __shared__ float Bs[54*128];
  __shared__ float As[54*64];
  __shared__ float bias_s[64];
  int img = blockIdx.z;
  const float* src = (img < 2) ? (q + (size_t)img*6*HW) : (k + (size_t)(img-2)*6*HW);
  int y0 = blockIdx.y*4, x0 = blockIdx.x*32;
  int tid = threadIdx.x;
  for (int e = tid; e < 54*64; e += 256) {
    int kk = e >> 6, co = e & 63;
    int ci = kk/9, tap = kk%9;
    As[e] = w1[(co*6 + ci)*9 + tap];
  }
  if (tid < 64) bias_s[tid] = b1[tid];
  const float mean[6] = {0.485f,0.456f,0.406f,0.5f,0.5f,0.5f};
  const float istd[6] = {1.0f/0.229f,1.0f/0.224f,1.0f/0.225f,10.0f,10.0f,10.0f};
  for (int e = tid; e < 54*128; e += 256) {
    int kk = e >> 7, p = e & 127;
    int ci = kk/9, tap = kk%9;
    int dy = tap/3, dx = tap%3, r = p>>5, xx = p&31;
    int gy = y0 + r + dy - 1, gx = x0 + xx + dx - 1;
    float v = 0.f;
    if (gy >= 0 && gy < HH && gx >= 0 && gx < WW)
      v = (src[(ci*HH + gy)*WW + gx] - mean[ci]) * istd[ci];
    Bs[e] = v;
  }
  __syncthreads();
  int tp = tid & 15, tc = tid >> 4;
  float acc[4][8] = {};
#pragma unroll 6
  for (int kk = 0; kk < 54; kk++) {
    float4 a  = *(float4*)&As[kk*64 + tc*4];
    float4 v0 = *(float4*)&Bs[kk*128 + tp*4];
    float4 v1 = *(float4*)&Bs[kk*128 + 64 + tp*4];
    fma4x8(acc, a, v0, v1);
  }
  int rA = tp>>3, cb = (tp&7)*4;
#pragma unroll
  for (int i=0;i<4;i++){
    int co = tc*4 + i;
    float b = bias_s[co];
    float o[8];
#pragma unroll
    for (int j=0;j<8;j++) o[j] = fmaxf(acc[i][j] + b, 0.f);
    size_t rowb = ((size_t)(img*64+co)*HH);
    *(float4*)&X1[(rowb + y0 + rA)*WW + x0 + cb]     = make_float4(o[0],o[1],o[2],o[3]);
    *(float4*)&X1[(rowb + y0 + 2 + rA)*WW + x0 + cb] = make_float4(o[4],o[5],o[6],o[7]);
  }
}

// ---------------- conv2: 3x3 (64->64) + relu -- 64co x 256px tile (R12 version, passing) ----------------
__global__ __launch_bounds__(256) void conv2_kernel(const float* __restrict__ X1, const float* __restrict__ W2t,
                                                    const float* __restrict__ b2, float* __restrict__ X2) {
  __shared__ float Bs[36*256];
  __shared__ float As[36*64];
  __shared__ float bias_s[64];
  int img = blockIdx.z, y0 = blockIdx.y*8, x0 = blockIdx.x*32;
  int tid = threadIdx.x;
  if (tid < 64) bias_s[tid] = b2[tid];
  const float* src = X1 + (size_t)img*64*HW;
  int aoff[9];
#pragma unroll
  for (int j=0;j<9;j++){
    int e = tid + j*256;
    int kk = e >> 6, co = e & 63;
    int ci = kk/9, tap = kk%9;
    aoff[j] = (tap*64 + ci)*64 + co;
  }
  int boff[36];
#pragma unroll
  for (int j=0;j<36;j++){
    int e = tid + j*256;
    int kk = e >> 8, p = e & 255;
    int ci = kk/9, tap = kk%9;
    int dy = tap/3, dx = tap%3, r = p>>5, xx = p&31;
    int gy = y0 + r + dy - 1, gx = x0 + xx + dx - 1;
    bool ok = (gy >= 0 && gy < HH && gx >= 0 && gx < WW);
    boff[j] = ok ? (ci*HW + gy*WW + gx) : -1;
  }
  float aPre[9], bPre[36];
#pragma unroll
  for (int j=0;j<9;j++) aPre[j] = W2t[aoff[j]];
#pragma unroll
  for (int j=0;j<36;j++){ int o = boff[j]; bPre[j] = (o >= 0) ? src[o] : 0.f; }
  int tp = tid & 15, tc = tid >> 4;
  float acc[4][16] = {};
  for (int c0 = 0; c0 < 64; c0 += 4) {
    __syncthreads();
#pragma unroll
    for (int j=0;j<9;j++)  As[tid + j*256] = aPre[j];
#pragma unroll
    for (int j=0;j<36;j++) Bs[tid + j*256] = bPre[j];
    __syncthreads();
    if (c0 < 60) {
#pragma unroll
      for (int j=0;j<9;j++)  aPre[j] = W2t[aoff[j] + (c0+4)*64];
#pragma unroll
      for (int j=0;j<36;j++){ int o = boff[j]; bPre[j] = (o >= 0) ? src[(size_t)(c0+4)*HW + o] : 0.f; }
    }
#pragma unroll 4
    for (int kk = 0; kk < 36; kk++) {
      float4 a  = *(float4*)&As[kk*64 + tc*4];
      float4 v0 = *(float4*)&Bs[kk*256 + tp*4];
      float4 v1 = *(float4*)&Bs[kk*256 + 64 + tp*4];
      float4 v2 = *(float4*)&Bs[kk*256 + 128 + tp*4];
      float4 v3 = *(float4*)&Bs[kk*256 + 192 + tp*4];
      float av[4] = {a.x,a.y,a.z,a.w};
      float bv[16] = {v0.x,v0.y,v0.z,v0.w, v1.x,v1.y,v1.z,v1.w,
                      v2.x,v2.y,v2.z,v2.w, v3.x,v3.y,v3.z,v3.w};
#pragma unroll
      for (int i=0;i<4;i++)
#pragma unroll
        for (int jj=0;jj<16;jj++)
          acc[i][jj] = fmaf(av[i], bv[jj], acc[i][jj]);
    }
  }
#pragma unroll
  for (int i=0;i<4;i++){
    int co = tc*4 + i;
    float b = bias_s[co];
    size_t rowb = ((size_t)(img*64+co)*HH);
#pragma unroll
    for (int j4=0;j4<4;j4++){
      int p = j4*64 + tp*4;
      int r = p>>5, xx = p&31;
      float4 o4 = make_float4(fmaxf(acc[i][j4*4+0] + b, 0.f),
                              fmaxf(acc[i][j4*4+1] + b, 0.f),
                              fmaxf(acc[i][j4*4+2] + b, 0.f),
                              fmaxf(acc[i][j4*4+3] + b, 0.f));
      *(float4*)&X2[(rowb + y0 + r)*WW + x0 + xx] = o4;
    }
  }
}

// ---------------- conv3 (64->128,relu) + conv4 1x1 (128->16) + leaky -- 128co x 256px tile ----------------
// 8co x 16px/thread: 6 ds_read_b128 per 128 FMA (was 4 per 64) -> DS-issue bound drops 1.68x -> 1.26x.
// Conflict-free stride-64 frags; per-output FMA order over (c0,kk) and conv4 reduction order
// identical to R11/R12 -> F bit-identical.
__global__ __launch_bounds__(256) void conv3_kernel(const float* __restrict__ X2, const float* __restrict__ W3t,
                                                    const float* __restrict__ b3, const float* __restrict__ w4,
                                                    const float* __restrict__ b4, float* __restrict__ F) {
  __shared__ float smem[13824];    // Bs[36*256]=9216 | As[36*128]=4608; epilogue: w4s[2048] | red[2][256][17]=8704
  __shared__ float b3s[128];
  __shared__ float b4s[16];
  float* Bs = smem;
  float* As = smem + 9216;
  int img = blockIdx.z, y0 = blockIdx.y*8, x0 = blockIdx.x*32;
  int tid = threadIdx.x;
  if (tid < 128) b3s[tid] = b3[tid];
  if (tid < 16)  b4s[tid] = b4[tid];
  const float* src = X2 + (size_t)img*64*HW;
  int aoff[18];
#pragma unroll
  for (int j=0;j<18;j++){
    int e = tid + j*256;
    int kk = e >> 7, co = e & 127;
    int ci = kk/9, tap = kk%9;
    aoff[j] = (tap*64 + ci)*128 + co;
  }
  int boff[36];
#pragma unroll
  for (int j=0;j<36;j++){
    int e = tid + j*256;
    int kk = e >> 8, p = e & 255;
    int ci = kk/9, tap = kk%9;
    int dy = tap/3, dx = tap%3, r = p>>5, xx = p&31;
    int gy = y0 + r + dy - 1, gx = x0 + xx + dx - 1;
    bool ok = (gy >= 0 && gy < HH && gx >= 0 && gx < WW);
    boff[j] = ok ? (ci*HW + gy*WW + gx) : -1;
  }
  float aPre[18], bPre[36];
#pragma unroll
  for (int j=0;j<18;j++) aPre[j] = W3t[aoff[j]];
#pragma unroll
  for (int j=0;j<36;j++){ int o = boff[j]; bPre[j] = (o >= 0) ? src[o] : 0.f; }
  int tp = tid & 15, tc = tid >> 4;
  float acc[8][16] = {};
  for (int c0 = 0; c0 < 64; c0 += 4) {
    __syncthreads();
#pragma unroll
    for (int j=0;j<18;j++) As[tid + j*256] = aPre[j];
#pragma unroll
    for (int j=0;j<36;j++) Bs[tid + j*256] = bPre[j];
    __syncthreads();
    if (c0 < 60) {
#pragma unroll
      for (int j=0;j<18;j++) aPre[j] = W3t[aoff[j] + (c0+4)*128];
#pragma unroll
      for (int j=0;j<36;j++){ int o = boff[j]; bPre[j] = (o >= 0) ? src[(size_t)(c0+4)*HW + o] : 0.f; }
    }
#pragma unroll 2
    for (int kk = 0; kk < 36; kk++) {
      float4 a0 = *(float4*)&As[kk*128 + tc*4];
      float4 a1 = *(float4*)&As[kk*128 + 64 + tc*4];
      float4 v0 = *(float4*)&Bs[kk*256 + tp*4];
      float4 v1 = *(float4*)&Bs[kk*256 + 64 + tp*4];
      float4 v2 = *(float4*)&Bs[kk*256 + 128 + tp*4];
      float4 v3 = *(float4*)&Bs[kk*256 + 192 + tp*4];
      float av[8] = {a0.x,a0.y,a0.z,a0.w, a1.x,a1.y,a1.z,a1.w};
      float bv[16] = {v0.x,v0.y,v0.z,v0.w, v1.x,v1.y,v1.z,v1.w,
                      v2.x,v2.y,v2.z,v2.w, v3.x,v3.y,v3.z,v3.w};
#pragma unroll
      for (int i=0;i<8;i++)
#pragma unroll
        for (int jj=0;jj<16;jj++)
          acc[i][jj] = fmaf(av[i], bv[jj], acc[i][jj]);
    }
  }
  // bias + relu; co(i) = tc*4+i (i<4), 64+tc*4+(i-4) (i>=4)  -- same mapping as R11/R12
#pragma unroll
  for (int i=0;i<8;i++){
    int co = (i<4) ? (tc*4+i) : (64 + tc*4 + i - 4);
    float b = b3s[co];
#pragma unroll
    for (int jj=0;jj<16;jj++) acc[i][jj] = fmaxf(acc[i][jj] + b, 0.f);
  }
  // conv4 1x1 (128->16) + leaky; recycle smem: w4s + red[2][256][17]
  __syncthreads();
  float* w4s = smem;               // 2048
  float* red = smem + 2048;        // 8704  (total 10752 <= 13824)
  for (int e = tid; e < 2048; e += 256) w4s[e] = w4[e];
  __syncthreads();
  for (int op = 0; op < 8; op++) {
    float pout[2][16];
#pragma unroll
    for (int oo=0;oo<2;oo++){
      const float* wr = &w4s[(op*2+oo)*128];
      float wv[8];
#pragma unroll
      for (int i=0;i<8;i++) wv[i] = wr[(i<4) ? (tc*4+i) : (64 + tc*4 + i - 4)];
#pragma unroll
      for (int jj=0;jj<16;jj++){
        float s = 0.f;
#pragma unroll
        for (int i=0;i<8;i++) s = fmaf(wv[i], acc[i][jj], s);
        pout[oo][jj] = s;
      }
    }
    if (op) __syncthreads();
#pragma unroll
    for (int oo=0;oo<2;oo++)
#pragma unroll
      for (int jj=0;jj<16;jj++){
        int p = (jj>>2)*64 + tp*4 + (jj&3);
        red[(oo*256 + p)*17 + tc] = pout[oo][jj];
      }
    __syncthreads();
    for (int e = tid; e < 512; e += 256) {
      int oo = e >> 8, p = e & 255;
      float s = 0.f;
#pragma unroll
      for (int t=0;t<16;t++) s += red[(oo*256+p)*17 + t];
      int o = op*2 + oo;
      s += b4s[o];
      s = (s >= 0.f) ? s : 0.2f*s;
      int pr = p >> 5, px = p & 31;
      F[((size_t)(img*16 + o)*HH + y0+pr)*WW + x0+px] = s;
    }
  }
}

// ---------------- unfold + l2norm -> P (q), Kt (k, transposed), Ph/Pl (split fp16, all) ----------------
__global__ __launch_bounds__(256) void unfold_norm_kernel(const float* __restrict__ F, float* __restrict__ P,
                                                          float* __restrict__ Kt,
                                                          _Float16* __restrict__ Ph, _Float16* __restrict__ Pl) {
  __shared__ float tile[16*3*288];
  __shared__ float invn[96];
  int qy = blockIdx.x, img = blockIdx.y, tid = threadIdx.x;
  const float* src = F + (size_t)img*16*HW;
  for (int e = tid; e < 16*3*288; e += 256) {
    int c = e/864, rem = e%864;
    int kh = rem/288, xx = rem%288;
    tile[e] = src[((size_t)c*HH + qy*3+kh)*WW + xx];
  }
  __syncthreads();
  if (tid < 96) {
    float s = 0.f;
    for (int c=0;c<16;c++)
#pragma unroll
      for (int kh=0;kh<3;kh++)
#pragma unroll
        for (int kw=0;kw<3;kw++){
          float v = tile[(c*3+kh)*288 + tid*3+kw];
          s = fmaf(v, v, s);
        }
    invn[tid] = 1.f / fmaxf(sqrtf(s), 1e-12f);
  }
  __syncthreads();
  for (int e = tid; e < 96*160; e += 256) {
    int qx = e/160, d = e%160;
    float v = 0.f;
    if (d < 144) {
      int c = d/9, rem = d%9, kh = rem/3, kw = rem%3;
      v = tile[(c*3+kh)*288 + qx*3+kw] * invn[qx];
    }
    _Float16 hi;
    if (__builtin_fabsf(v) < 6.1035156e-5f) hi = (_Float16)0.f;
    else hi = (_Float16)v;
    float r = v - (float)hi;
    _Float16 lo = (_Float16)(r * 4096.f);
    size_t base = ((size_t)img*9216 + qy*96 + qx)*160 + d;
    Ph[base] = hi;
    Pl[base] = lo;
  }
  if (img < 2) {
    for (int e = tid; e < 96*144; e += 256) {
      int qx = e/144, d = e%144;
      int c = d/9, rem = d%9, kh = rem/3, kw = rem%3;
      P[((size_t)img*9216 + qy*96+qx)*144 + d] = tile[(c*3+kh)*288 + qx*3+kw] * invn[qx];
    }
  } else {
    for (int e = tid; e < 96*144; e += 256) {
      int d = e/96, qx = e%96;
      int c = d/9, rem = d%9, kh = rem/3, kw = rem%3;
      Kt[((size_t)(img-2)*144 + d)*9216 + qy*96 + qx] = tile[(c*3+kh)*288 + qx*3+kw] * invn[qx];
    }
  }
}

// ---------------- pass A: split-fp16 MFMA scores -> per-(query, 128-key-tile) maxima (R11 TM layout) ----------------
__global__ __launch_bounds__(256) void passA_kernel(const _Float16* __restrict__ Ph,
                                                    const _Float16* __restrict__ Pl,
                                                    float* __restrict__ TM) {
  int qg = blockIdx.x, part = blockIdx.y, b = blockIdx.z;
  int tid = threadIdx.x;
  int w = tid >> 6, lane = tid & 63;
  int quad = lane >> 4, lm = lane & 15;
  int m0 = qg*128 + w*32;
  const _Float16* Phq = Ph + (size_t)b*9216*160;
  const _Float16* Plq = Pl + (size_t)b*9216*160;
  const _Float16* Phk = Ph + (size_t)(2+b)*9216*160;
  const _Float16* Plk = Pl + (size_t)(2+b)*9216*160;
  f16x8 qh[2][5], ql[2][5];
#pragma unroll
  for (int ms=0; ms<2; ms++)
#pragma unroll
    for (int kc=0; kc<5; kc++){
      size_t off = (size_t)(m0 + ms*16 + lm)*160 + kc*32 + quad*8;
      qh[ms][kc] = *(const f16x8*)(Phq + off);
      ql[ms][kc] = *(const f16x8*)(Plq + off);
    }
  for (int t = 0; t < 12; t++) {
    int lt = part*12 + t;
    int l0 = lt*128;
    float rmax[2] = {-3e38f, -3e38f};
#pragma unroll
    for (int ls=0; ls<8; ls++){
      size_t rowoff = (size_t)(l0 + ls*16 + lm)*160 + quad*8;
      f32x4 accA[2] = {{0.f,0.f,0.f,0.f},{0.f,0.f,0.f,0.f}};
      f32x4 accB[2] = {{0.f,0.f,0.f,0.f},{0.f,0.f,0.f,0.f}};
#pragma unroll
      for (int kc=0; kc<5; kc++){
        f16x8 ahv = *(const f16x8*)(Phk + rowoff + kc*32);
        f16x8 alv = *(const f16x8*)(Plk + rowoff + kc*32);
#pragma unroll
        for (int ms=0; ms<2; ms++){
          accA[ms] = __builtin_amdgcn_mfma_f32_16x16x32_f16(ahv, qh[ms][kc], accA[ms], 0, 0, 0);
          accB[ms] = __builtin_amdgcn_mfma_f32_16x16x32_f16(ahv, ql[ms][kc], accB[ms], 0, 0, 0);
          accB[ms] = __builtin_amdgcn_mfma_f32_16x16x32_f16(alv, qh[ms][kc], accB[ms], 0, 0, 0);
        }
      }
#pragma unroll
      for (int ms=0; ms<2; ms++){
        float m01 = fmaxf(accA[ms][0] + accB[ms][0]*2.44140625e-4f,
                          accA[ms][1] + accB[ms][1]*2.44140625e-4f);
        float m23 = fmaxf(accA[ms][2] + accB[ms][2]*2.44140625e-4f,
                          accA[ms][3] + accB[ms][3]*2.44140625e-4f);
        rmax[ms] = fmaxf(rmax[ms], fmaxf(m01, m23));
      }
    }
#pragma unroll
    for (int ms=0; ms<2; ms++){
      float v = rmax[ms];
      v = fmaxf(v, __shfl_xor(v, 16, 64));
      v = fmaxf(v, __shfl_xor(v, 32, 64));
      if (quad == 0) TM[((size_t)(b*72 + lt))*9216 + m0 + ms*16 + lm] = v;
    }
  }
}

// ---------------- pass B: exact fp32 recheck of candidate tiles (coalesced via Kt, R11 TM layout) ----------------
__global__ __launch_bounds__(128) void passB_kernel(const float* __restrict__ P,
                                                    const float* __restrict__ Kt,
                                                    const float* __restrict__ TM,
                                                    float* __restrict__ out) {
  __shared__ float qrow[144];
  __shared__ float tmx[72];
  __shared__ float rv[128];
  __shared__ int   ri[128];
  int m = blockIdx.x, b = blockIdx.y, tid = threadIdx.x;
  const float* Q = P + ((size_t)(b*9216) + m)*144;
  const float* Kb = Kt + (size_t)b*144*9216;
  if (tid < 36) *(float4*)&qrow[tid*4] = *(const float4*)&Q[tid*4];
  if (tid < 72) tmx[tid] = TM[((size_t)(b*72 + tid))*9216 + m];
  __syncthreads();
  float M = -3e38f;
#pragma unroll 8
  for (int t = 0; t < 72; t++) M = fmaxf(M, tmx[t]);
  float T = M - 1e-4f;
  float bv = -3e38f; int bi = 0;
  for (int lt = 0; lt < 72; lt++) {
    if (tmx[lt] < T) continue;
    int l = lt*128 + tid;
    float s = 0.f;
#pragma unroll 16
    for (int d = 0; d < 144; d++)
      s = fmaf(Kb[(size_t)d*9216 + l], qrow[d], s);
    if (s > bv) { bv = s; bi = l; }
  }
  rv[tid] = bv; ri[tid] = bi;
  __syncthreads();
  for (int off = 64; off > 0; off >>= 1) {
    if (tid < off) {
      float v2 = rv[tid+off]; int i2 = ri[tid+off];
      if (v2 > rv[tid] || (v2 == rv[tid] && i2 < ri[tid])) { rv[tid] = v2; ri[tid] = i2; }
    }
    __syncthreads();
  }
  if (tid == 0) {
    out[(size_t)b*9216 + m] = rv[0];
    out[2*9216 + (size_t)b*9216 + m] = (float)ri[0];
  }
}

// ---------------- launcher ----------------
extern "C" void kernel_launch(void* const* d_in, const int* in_sizes, int n_in,
                              void* d_out, int out_size, void* d_ws, size_t ws_size,
                              hipStream_t stream) {
  (void)in_sizes; (void)n_in; (void)out_size; (void)ws_size;
  const float* query = (const float*)d_in[0];
  const float* key   = (const float*)d_in[1];
  const float* w1 = (const float*)d_in[3];
  const float* b1 = (const float*)d_in[4];
  const float* w2 = (const float*)d_in[5];
  const float* b2 = (const float*)d_in[6];
  const float* w3 = (const float*)d_in[7];
  const float* b3 = (const float*)d_in[8];
  const float* w4 = (const float*)d_in[9];
  const float* b4 = (const float*)d_in[10];

  float* ws = (float*)d_ws;
  size_t oX1  = 0;
  size_t oX2  = oX1 + (size_t)4*64*HW;
  size_t oF   = oX2 + (size_t)4*64*HW;
  size_t oP   = oF  + (size_t)4*16*HW;
  size_t oW2t = oP  + (size_t)2*9216*144;
  size_t oW3t = oW2t + (size_t)9*64*64;
  float* X1  = ws + oX1;
  float* X2  = ws + oX2;
  float* F   = ws + oF;
  float* P   = ws + oP;
  float* W2t = ws + oW2t;
  float* W3t = ws + oW3t;
  _Float16* Ph = (_Float16*)(ws + oX1);
  _Float16* Pl = (_Float16*)(ws + oX1 + 3*1024*1024);
  float*    Kt = ws + oX1 + 6*1024*1024;
  float*    TM = ws + oX1 + 9*1024*1024;

  hipLaunchKernelGGL(prep_kernel,        dim3(64),      dim3(256), 0, stream, w2, w3, W2t, W3t);
  hipLaunchKernelGGL(conv1_kernel,       dim3(9,72,4),  dim3(256), 0, stream, query, key, w1, b1, X1);
  hipLaunchKernelGGL(conv2_kernel,       dim3(9,36,4),  dim3(256), 0, stream, X1, W2t, b2, X2);
  hipLaunchKernelGGL(conv3_kernel,       dim3(9,36,4),  dim3(256), 0, stream, X2, W3t, b3, w4, b4, F);
  hipLaunchKernelGGL(unfold_norm_kernel, dim3(96,4),    dim3(256), 0, stream, F, P, Kt, Ph, Pl);
  hipLaunchKernelGGL(passA_kernel,       dim3(72,6,2),  dim3(256), 0, stream, Ph, Pl, TM);
  hipLaunchKernelGGL(passB_kernel,       dim3(9216,2),  dim3(128), 0, stream, P, Kt, TM, (float*)d_out);
}

// Round 14
// 1730.813 us; speedup vs baseline: 1.1069x; 1.1069x over previous
//
#include <hip/hip_runtime.h>

#define HH 288
#define WW 288
#define HW (HH*WW)

using f16x8  = __attribute__((ext_vector_type(8))) _Float16;
using f32x4  = __attribute__((ext_vector_type(4))) float;

// ---------------- helpers ----------------
__device__ __forceinline__ void fma4x8(float acc[4][8], const float4 a, const float4 b0, const float4 b1) {
  float av[4] = {a.x,a.y,a.z,a.w};
  float bv[8] = {b0.x,b0.y,b0.z,b0.w,b1.x,b1.y,b1.z,b1.w};
#pragma unroll
  for (int i=0;i<4;i++)
#pragma unroll
    for (int j=0;j<8;j++)
      acc[i][j] = fmaf(av[i], bv[j], acc[i][j]);
}

__device__ __forceinline__ void fma8x8(float acc[8][8], const float4 a0, const float4 a1,
                                       const float4 b0, const float4 b1) {
  float av[8] = {a0.x,a0.y,a0.z,a0.w,a1.x,a1.y,a1.z,a1.w};
  float bv[8] = {b0.x,b0.y,b0.z,b0.w,b1.x,b1.y,b1.z,b1.w};
#pragma unroll
  for (int i=0;i<8;i++)
#pragma unroll
    for (int j=0;j<8;j++)
      acc[i][j] = fmaf(av[i], bv[j], acc[i][j]);
}

// ---------------- prep: W2t/W3t fp32 transposes ----------------
__global__ __launch_bounds__(256) void prep_kernel(const float* __restrict__ w2, const float* __restrict__ w3,
                                                   float* __restrict__ W2t, float* __restrict__ W3t) {
  int tid = blockIdx.x*256 + threadIdx.x;
  int stride = gridDim.x*256;
  for (int e = tid; e < 9*64*64; e += stride) {
    int tap = e / 4096, ci = (e >> 6) & 63, co = e & 63;
    W2t[e] = w2[(co*64 + ci)*9 + tap];
  }
  for (int e = tid; e < 9*64*128; e += stride) {
    int tap = e / 8192, ci = (e >> 7) & 63, co = e & 127;
    W3t[e] = w3[(co*64 + ci)*9 + tap];
  }
}

// ---------------- conv1: sub_mean + 3x3 (6->64) + relu (R9 version, passing) ----------------
__global__ __launch_bounds__(256) void conv1_kernel(const float* __restrict__ q, const float* __restrict__ k,
                                                    const float* __restrict__ w1, const float* __restrict__ b1,
                                                    float* __restrict__ X1) {
  __shared__ float Bs[54*128];
  __shared__ float As[54*64];
  __shared__ float bias_s[64];
  int img = blockIdx.z;
  const float* src = (img < 2) ? (q + (size_t)img*6*HW) : (k + (size_t)(img-2)*6*HW);
  int y0 = blockIdx.y*4, x0 = blockIdx.x*32;
  int tid = threadIdx.x;
  for (int e = tid; e < 54*64; e += 256) {
    int kk = e >> 6, co = e & 63;
    int ci = kk/9, tap = kk%9;
    As[e] = w1[(co*6 + ci)*9 + tap];
  }
  if (tid < 64) bias_s[tid] = b1[tid];
  const float mean[6] = {0.485f,0.456f,0.406f,0.5f,0.5f,0.5f};
  const float istd[6] = {1.0f/0.229f,1.0f/0.224f,1.0f/0.225f,10.0f,10.0f,10.0f};
  for (int e = tid; e < 54*128; e += 256) {
    int kk = e >> 7, p = e & 127;
    int ci = kk/9, tap = kk%9;
    int dy = tap/3, dx = tap%3, r = p>>5, xx = p&31;
    int gy = y0 + r + dy - 1, gx = x0 + xx + dx - 1;
    float v = 0.f;
    if (gy >= 0 && gy < HH && gx >= 0 && gx < WW)
      v = (src[(ci*HH + gy)*WW + gx] - mean[ci]) * istd[ci];
    Bs[e] = v;
  }
  __syncthreads();
  int tp = tid & 15, tc = tid >> 4;
  float acc[4][8] = {};
#pragma unroll 6
  for (int kk = 0; kk < 54; kk++) {
    float4 a  = *(float4*)&As[kk*64 + tc*4];
    float4 v0 = *(float4*)&Bs[kk*128 + tp*4];
    float4 v1 = *(float4*)&Bs[kk*128 + 64 + tp*4];
    fma4x8(acc, a, v0, v1);
  }
  int rA = tp>>3, cb = (tp&7)*4;
#pragma unroll
  for (int i=0;i<4;i++){
    int co = tc*4 + i;
    float b = bias_s[co];
    float o[8];
#pragma unroll
    for (int j=0;j<8;j++) o[j] = fmaxf(acc[i][j] + b, 0.f);
    size_t rowb = ((size_t)(img*64+co)*HH);
    *(float4*)&X1[(rowb + y0 + rA)*WW + x0 + cb]     = make_float4(o[0],o[1],o[2],o[3]);
    *(float4*)&X1[(rowb + y0 + 2 + rA)*WW + x0 + cb] = make_float4(o[4],o[5],o[6],o[7]);
  }
}

// ---------------- conv2: 3x3 (64->64) + relu -- 64co x 256px tile (R12/R13 version, passing) ----------------
__global__ __launch_bounds__(256) void conv2_kernel(const float* __restrict__ X1, const float* __restrict__ W2t,
                                                    const float* __restrict__ b2, float* __restrict__ X2) {
  __shared__ float Bs[36*256];
  __shared__ float As[36*64];
  __shared__ float bias_s[64];
  int img = blockIdx.z, y0 = blockIdx.y*8, x0 = blockIdx.x*32;
  int tid = threadIdx.x;
  if (tid < 64) bias_s[tid] = b2[tid];
  const float* src = X1 + (size_t)img*64*HW;
  int aoff[9];
#pragma unroll
  for (int j=0;j<9;j++){
    int e = tid + j*256;
    int kk = e >> 6, co = e & 63;
    int ci = kk/9, tap = kk%9;
    aoff[j] = (tap*64 + ci)*64 + co;
  }
  int boff[36];
#pragma unroll
  for (int j=0;j<36;j++){
    int e = tid + j*256;
    int kk = e >> 8, p = e & 255;
    int ci = kk/9, tap = kk%9;
    int dy = tap/3, dx = tap%3, r = p>>5, xx = p&31;
    int gy = y0 + r + dy - 1, gx = x0 + xx + dx - 1;
    bool ok = (gy >= 0 && gy < HH && gx >= 0 && gx < WW);
    boff[j] = ok ? (ci*HW + gy*WW + gx) : -1;
  }
  float aPre[9], bPre[36];
#pragma unroll
  for (int j=0;j<9;j++) aPre[j] = W2t[aoff[j]];
#pragma unroll
  for (int j=0;j<36;j++){ int o = boff[j]; bPre[j] = (o >= 0) ? src[o] : 0.f; }
  int tp = tid & 15, tc = tid >> 4;
  float acc[4][16] = {};
  for (int c0 = 0; c0 < 64; c0 += 4) {
    __syncthreads();
#pragma unroll
    for (int j=0;j<9;j++)  As[tid + j*256] = aPre[j];
#pragma unroll
    for (int j=0;j<36;j++) Bs[tid + j*256] = bPre[j];
    __syncthreads();
    if (c0 < 60) {
#pragma unroll
      for (int j=0;j<9;j++)  aPre[j] = W2t[aoff[j] + (c0+4)*64];
#pragma unroll
      for (int j=0;j<36;j++){ int o = boff[j]; bPre[j] = (o >= 0) ? src[(size_t)(c0+4)*HW + o] : 0.f; }
    }
#pragma unroll 4
    for (int kk = 0; kk < 36; kk++) {
      float4 a  = *(float4*)&As[kk*64 + tc*4];
      float4 v0 = *(float4*)&Bs[kk*256 + tp*4];
      float4 v1 = *(float4*)&Bs[kk*256 + 64 + tp*4];
      float4 v2 = *(float4*)&Bs[kk*256 + 128 + tp*4];
      float4 v3 = *(float4*)&Bs[kk*256 + 192 + tp*4];
      float av[4] = {a.x,a.y,a.z,a.w};
      float bv[16] = {v0.x,v0.y,v0.z,v0.w, v1.x,v1.y,v1.z,v1.w,
                      v2.x,v2.y,v2.z,v2.w, v3.x,v3.y,v3.z,v3.w};
#pragma unroll
      for (int i=0;i<4;i++)
#pragma unroll
        for (int jj=0;jj<16;jj++)
          acc[i][jj] = fmaf(av[i], bv[jj], acc[i][jj]);
    }
  }
#pragma unroll
  for (int i=0;i<4;i++){
    int co = tc*4 + i;
    float b = bias_s[co];
    size_t rowb = ((size_t)(img*64+co)*HH);
#pragma unroll
    for (int j4=0;j4<4;j4++){
      int p = j4*64 + tp*4;
      int r = p>>5, xx = p&31;
      float4 o4 = make_float4(fmaxf(acc[i][j4*4+0] + b, 0.f),
                              fmaxf(acc[i][j4*4+1] + b, 0.f),
                              fmaxf(acc[i][j4*4+2] + b, 0.f),
                              fmaxf(acc[i][j4*4+3] + b, 0.f));
      *(float4*)&X2[(rowb + y0 + r)*WW + x0 + xx] = o4;
    }
  }
}

// ---------------- conv3 (64->128,relu) + conv4 1x1 (128->16) + leaky (R11/R12 version: 673 us, passing) ----
__global__ __launch_bounds__(256) void conv3_kernel(const float* __restrict__ X2, const float* __restrict__ W3t,
                                                    const float* __restrict__ b3, const float* __restrict__ w4,
                                                    const float* __restrict__ b4, float* __restrict__ F) {
  __shared__ float smem[9216];     // Bs[36*128] | As[36*128]; epilogue: w4s[2048] | red[2][128][17]
  __shared__ float b3s[128];
  __shared__ float b4s[16];
  float* Bs = smem;
  float* As = smem + 4608;
  int img = blockIdx.z, y0 = blockIdx.y*4, x0 = blockIdx.x*32;
  int tid = threadIdx.x;
  if (tid < 128) b3s[tid] = b3[tid];
  if (tid < 16)  b4s[tid] = b4[tid];
  const float* src = X2 + (size_t)img*64*HW;
  int aoff[18];
#pragma unroll
  for (int j=0;j<18;j++){
    int e = tid + j*256;
    int kk = e >> 7, co = e & 127;
    int ci = kk/9, tap = kk%9;
    aoff[j] = (tap*64 + ci)*128 + co;
  }
  int boff[18];
#pragma unroll
  for (int j=0;j<18;j++){
    int e = tid + j*256;
    int kk = e >> 7, p = e & 127;
    int ci = kk/9, tap = kk%9;
    int dy = tap/3, dx = tap%3, r = p>>5, xx = p&31;
    int gy = y0 + r + dy - 1, gx = x0 + xx + dx - 1;
    bool ok = (gy >= 0 && gy < HH && gx < WW && gx >= 0);
    boff[j] = ok ? (ci*HW + gy*WW + gx) : -1;
  }
  float aPre[18], bPre[18];
#pragma unroll
  for (int j=0;j<18;j++) aPre[j] = W3t[aoff[j]];
#pragma unroll
  for (int j=0;j<18;j++){ int o = boff[j]; bPre[j] = (o >= 0) ? src[o] : 0.f; }
  int tp = tid & 15, tc = tid >> 4;
  float acc[8][8] = {};
  for (int c0 = 0; c0 < 64; c0 += 4) {
    __syncthreads();
#pragma unroll
    for (int j=0;j<18;j++) As[tid + j*256] = aPre[j];
#pragma unroll
    for (int j=0;j<18;j++) Bs[tid + j*256] = bPre[j];
    __syncthreads();
    if (c0 < 60) {
#pragma unroll
      for (int j=0;j<18;j++) aPre[j] = W3t[aoff[j] + (c0+4)*128];
#pragma unroll
      for (int j=0;j<18;j++){ int o = boff[j]; bPre[j] = (o >= 0) ? src[(size_t)(c0+4)*HW + o] : 0.f; }
    }
#pragma unroll 4
    for (int kk = 0; kk < 36; kk++) {
      float4 a0 = *(float4*)&As[kk*128 + tc*4];
      float4 a1 = *(float4*)&As[kk*128 + 64 + tc*4];
      float4 v0 = *(float4*)&Bs[kk*128 + tp*4];
      float4 v1 = *(float4*)&Bs[kk*128 + 64 + tp*4];
      fma8x8(acc, a0, a1, v0, v1);
    }
  }
#pragma unroll
  for (int i=0;i<8;i++){
    int co = (i<4) ? (tc*4+i) : (64 + tc*4 + i - 4);
    float b = b3s[co];
#pragma unroll
    for (int j=0;j<8;j++) acc[i][j] = fmaxf(acc[i][j] + b, 0.f);
  }
  __syncthreads();
  float* w4s = smem;               // 2048
  float* red = smem + 2048;        // [2][128][17] = 4352
  for (int e = tid; e < 2048; e += 256) w4s[e] = w4[e];
  __syncthreads();
  for (int op = 0; op < 8; op++) {
    float pout[2][8];
#pragma unroll
    for (int oo=0;oo<2;oo++){
      const float* wr = &w4s[(op*2+oo)*128];
      float wv[8];
#pragma unroll
      for (int i=0;i<8;i++) wv[i] = wr[(i<4) ? (tc*4+i) : (64 + tc*4 + i - 4)];
#pragma unroll
      for (int j=0;j<8;j++){
        float s = 0.f;
#pragma unroll
        for (int i=0;i<8;i++) s = fmaf(wv[i], acc[i][j], s);
        pout[oo][j] = s;
      }
    }
    if (op) __syncthreads();
#pragma unroll
    for (int oo=0;oo<2;oo++)
#pragma unroll
      for (int j=0;j<8;j++){
        int px = (j<4) ? (tp*4+j) : (64 + tp*4 + j - 4);
        red[(oo*128 + px)*17 + tc] = pout[oo][j];
      }
    __syncthreads();
    {
      int oo = tid >> 7, p = tid & 127;
      float s = 0.f;
#pragma unroll
      for (int t=0;t<16;t++) s += red[(oo*128+p)*17 + t];
      int o = op*2 + oo;
      s += b4s[o];
      s = (s >= 0.f) ? s : 0.2f*s;
      int pr = p >> 5, px = p & 31;
      F[((size_t)(img*16 + o)*HH + y0+pr)*WW + x0+px] = s;
    }
  }
}

// ---------------- unfold + l2norm -> P (q), Kt (k, transposed), Ph/Pl (split fp16, all) ----------------
__global__ __launch_bounds__(256) void unfold_norm_kernel(const float* __restrict__ F, float* __restrict__ P,
                                                          float* __restrict__ Kt,
                                                          _Float16* __restrict__ Ph, _Float16* __restrict__ Pl) {
  __shared__ float tile[16*3*288];
  __shared__ float invn[96];
  int qy = blockIdx.x, img = blockIdx.y, tid = threadIdx.x;
  const float* src = F + (size_t)img*16*HW;
  for (int e = tid; e < 16*3*288; e += 256) {
    int c = e/864, rem = e%864;
    int kh = rem/288, xx = rem%288;
    tile[e] = src[((size_t)c*HH + qy*3+kh)*WW + xx];
  }
  __syncthreads();
  if (tid < 96) {
    float s = 0.f;
    for (int c=0;c<16;c++)
#pragma unroll
      for (int kh=0;kh<3;kh++)
#pragma unroll
        for (int kw=0;kw<3;kw++){
          float v = tile[(c*3+kh)*288 + tid*3+kw];
          s = fmaf(v, v, s);
        }
    invn[tid] = 1.f / fmaxf(sqrtf(s), 1e-12f);
  }
  __syncthreads();
  for (int e = tid; e < 96*160; e += 256) {
    int qx = e/160, d = e%160;
    float v = 0.f;
    if (d < 144) {
      int c = d/9, rem = d%9, kh = rem/3, kw = rem%3;
      v = tile[(c*3+kh)*288 + qx*3+kw] * invn[qx];
    }
    _Float16 hi;
    if (__builtin_fabsf(v) < 6.1035156e-5f) hi = (_Float16)0.f;
    else hi = (_Float16)v;
    float r = v - (float)hi;
    _Float16 lo = (_Float16)(r * 4096.f);
    size_t base = ((size_t)img*9216 + qy*96 + qx)*160 + d;
    Ph[base] = hi;
    Pl[base] = lo;
  }
  if (img < 2) {
    for (int e = tid; e < 96*144; e += 256) {
      int qx = e/144, d = e%144;
      int c = d/9, rem = d%9, kh = rem/3, kw = rem%3;
      P[((size_t)img*9216 + qy*96+qx)*144 + d] = tile[(c*3+kh)*288 + qx*3+kw] * invn[qx];
    }
  } else {
    for (int e = tid; e < 96*144; e += 256) {
      int d = e/96, qx = e%96;
      int c = d/9, rem = d%9, kh = rem/3, kw = rem%3;
      Kt[((size_t)(img-2)*144 + d)*9216 + qy*96 + qx] = tile[(c*3+kh)*288 + qx*3+kw] * invn[qx];
    }
  }
}

// ---------------- pass A: split-fp16 MFMA scores -> per-(query, 128-key-tile) maxima (R11 TM layout) ----------------
__global__ __launch_bounds__(256) void passA_kernel(const _Float16* __restrict__ Ph,
                                                    const _Float16* __restrict__ Pl,
                                                    float* __restrict__ TM) {
  int qg = blockIdx.x, part = blockIdx.y, b = blockIdx.z;
  int tid = threadIdx.x;
  int w = tid >> 6, lane = tid & 63;
  int quad = lane >> 4, lm = lane & 15;
  int m0 = qg*128 + w*32;
  const _Float16* Phq = Ph + (size_t)b*9216*160;
  const _Float16* Plq = Pl + (size_t)b*9216*160;
  const _Float16* Phk = Ph + (size_t)(2+b)*9216*160;
  const _Float16* Plk = Pl + (size_t)(2+b)*9216*160;
  f16x8 qh[2][5], ql[2][5];
#pragma unroll
  for (int ms=0; ms<2; ms++)
#pragma unroll
    for (int kc=0; kc<5; kc++){
      size_t off = (size_t)(m0 + ms*16 + lm)*160 + kc*32 + quad*8;
      qh[ms][kc] = *(const f16x8*)(Phq + off);
      ql[ms][kc] = *(const f16x8*)(Plq + off);
    }
  for (int t = 0; t < 12; t++) {
    int lt = part*12 + t;
    int l0 = lt*128;
    float rmax[2] = {-3e38f, -3e38f};
#pragma unroll
    for (int ls=0; ls<8; ls++){
      size_t rowoff = (size_t)(l0 + ls*16 + lm)*160 + quad*8;
      f32x4 accA[2] = {{0.f,0.f,0.f,0.f},{0.f,0.f,0.f,0.f}};
      f32x4 accB[2] = {{0.f,0.f,0.f,0.f},{0.f,0.f,0.f,0.f}};
#pragma unroll
      for (int kc=0; kc<5; kc++){
        f16x8 ahv = *(const f16x8*)(Phk + rowoff + kc*32);
        f16x8 alv = *(const f16x8*)(Plk + rowoff + kc*32);
#pragma unroll
        for (int ms=0; ms<2; ms++){
          accA[ms] = __builtin_amdgcn_mfma_f32_16x16x32_f16(ahv, qh[ms][kc], accA[ms], 0, 0, 0);
          accB[ms] = __builtin_amdgcn_mfma_f32_16x16x32_f16(ahv, ql[ms][kc], accB[ms], 0, 0, 0);
          accB[ms] = __builtin_amdgcn_mfma_f32_16x16x32_f16(alv, qh[ms][kc], accB[ms], 0, 0, 0);
        }
      }
#pragma unroll
      for (int ms=0; ms<2; ms++){
        float m01 = fmaxf(accA[ms][0] + accB[ms][0]*2.44140625e-4f,
                          accA[ms][1] + accB[ms][1]*2.44140625e-4f);
        float m23 = fmaxf(accA[ms][2] + accB[ms][2]*2.44140625e-4f,
                          accA[ms][3] + accB[ms][3]*2.44140625e-4f);
        rmax[ms] = fmaxf(rmax[ms], fmaxf(m01, m23));
      }
    }
#pragma unroll
    for (int ms=0; ms<2; ms++){
      float v = rmax[ms];
      v = fmaxf(v, __shfl_xor(v, 16, 64));
      v = fmaxf(v, __shfl_xor(v, 32, 64));
      if (quad == 0) TM[((size_t)(b*72 + lt))*9216 + m0 + ms*16 + lm] = v;
    }
  }
}

// ---------------- pass B: exact fp32 recheck of candidate tiles (coalesced via Kt, R11 TM layout) ----------------
__global__ __launch_bounds__(128) void passB_kernel(const float* __restrict__ P,
                                                    const float* __restrict__ Kt,
                                                    const float* __restrict__ TM,
                                                    float* __restrict__ out) {
  __shared__ float qrow[144];
  __shared__ float tmx[72];
  __shared__ float rv[128];
  __shared__ int   ri[128];
  int m = blockIdx.x, b = blockIdx.y, tid = threadIdx.x;
  const float* Q = P + ((size_t)(b*9216) + m)*144;
  const float* Kb = Kt + (size_t)b*144*9216;
  if (tid < 36) *(float4*)&qrow[tid*4] = *(const float4*)&Q[tid*4];
  if (tid < 72) tmx[tid] = TM[((size_t)(b*72 + tid))*9216 + m];
  __syncthreads();
  float M = -3e38f;
#pragma unroll 8
  for (int t = 0; t < 72; t++) M = fmaxf(M, tmx[t]);
  float T = M - 1e-4f;
  float bv = -3e38f; int bi = 0;
  for (int lt = 0; lt < 72; lt++) {
    if (tmx[lt] < T) continue;
    int l = lt*128 + tid;
    float s = 0.f;
#pragma unroll 16
    for (int d = 0; d < 144; d++)
      s = fmaf(Kb[(size_t)d*9216 + l], qrow[d], s);
    if (s > bv) { bv = s; bi = l; }
  }
  rv[tid] = bv; ri[tid] = bi;
  __syncthreads();
  for (int off = 64; off > 0; off >>= 1) {
    if (tid < off) {
      float v2 = rv[tid+off]; int i2 = ri[tid+off];
      if (v2 > rv[tid] || (v2 == rv[tid] && i2 < ri[tid])) { rv[tid] = v2; ri[tid] = i2; }
    }
    __syncthreads();
  }
  if (tid == 0) {
    out[(size_t)b*9216 + m] = rv[0];
    out[2*9216 + (size_t)b*9216 + m] = (float)ri[0];
  }
}

// ---------------- launcher ----------------
extern "C" void kernel_launch(void* const* d_in, const int* in_sizes, int n_in,
                              void* d_out, int out_size, void* d_ws, size_t ws_size,
                              hipStream_t stream) {
  (void)in_sizes; (void)n_in; (void)out_size; (void)ws_size;
  const float* query = (const float*)d_in[0];
  const float* key   = (const float*)d_in[1];
  const float* w1 = (const float*)d_in[3];
  const float* b1 = (const float*)d_in[4];
  const float* w2 = (const float*)d_in[5];
  const float* b2 = (const float*)d_in[6];
  const float* w3 = (const float*)d_in[7];
  const float* b3 = (const float*)d_in[8];
  const float* w4 = (const float*)d_in[9];
  const float* b4 = (const float*)d_in[10];

  float* ws = (float*)d_ws;
  size_t oX1  = 0;
  size_t oX2  = oX1 + (size_t)4*64*HW;
  size_t oF   = oX2 + (size_t)4*64*HW;
  size_t oP   = oF  + (size_t)4*16*HW;
  size_t oW2t = oP  + (size_t)2*9216*144;
  size_t oW3t = oW2t + (size_t)9*64*64;
  float* X1  = ws + oX1;
  float* X2  = ws + oX2;
  float* F   = ws + oF;
  float* P   = ws + oP;
  float* W2t = ws + oW2t;
  float* W3t = ws + oW3t;
  _Float16* Ph = (_Float16*)(ws + oX1);
  _Float16* Pl = (_Float16*)(ws + oX1 + 3*1024*1024);
  float*    Kt = ws + oX1 + 6*1024*1024;
  float*    TM = ws + oX1 + 9*1024*1024;

  hipLaunchKernelGGL(prep_kernel,        dim3(64),      dim3(256), 0, stream, w2, w3, W2t, W3t);
  hipLaunchKernelGGL(conv1_kernel,       dim3(9,72,4),  dim3(256), 0, stream, query, key, w1, b1, X1);
  hipLaunchKernelGGL(conv2_kernel,       dim3(9,36,4),  dim3(256), 0, stream, X1, W2t, b2, X2);
  hipLaunchKernelGGL(conv3_kernel,       dim3(9,72,4),  dim3(256), 0, stream, X2, W3t, b3, w4, b4, F);
  hipLaunchKernelGGL(unfold_norm_kernel, dim3(96,4),    dim3(256), 0, stream, F, P, Kt, Ph, Pl);
  hipLaunchKernelGGL(passA_kernel,       dim3(72,6,2),  dim3(256), 0, stream, Ph, Pl, TM);
  hipLaunchKernelGGL(passB_kernel,       dim3(9216,2),  dim3(128), 0, stream, P, Kt, TM, (float*)d_out);
}